// Round 1
// 474.534 us; speedup vs baseline: 1.0419x; 1.0419x over previous
//
#include <hip/hip_runtime.h>
#include <cstdint>
#include <cstddef>

// ---------------- types ----------------
typedef __attribute__((ext_vector_type(8))) _Float16 half8;   // MFMA f16 A/B frag (4 VGPRs)
typedef __attribute__((ext_vector_type(4))) _Float16 half4;
typedef __attribute__((ext_vector_type(4))) float    floatx4; // MFMA C/D frag

static constexpr int B_ROWS = 16384;
static constexpr int IN_DIM = 256;
static constexpr int H_DIM  = 512;
static constexpr int NB     = 16;

__device__ __forceinline__ float fast_tanh(float x) {
  float ax = fabsf(x);
  float e  = __expf(2.0f * ax);             // e >= 1, inf-safe
  float t  = 1.0f - 2.0f / (e + 1.0f);
  return copysignf(t, x);
}

// async global->LDS, 16B per lane; LDS dest must be wave-uniform base + lane*16
__device__ __forceinline__ void gld16(const void* g, void* l) {
  __builtin_amdgcn_global_load_lds(
      (const __attribute__((address_space(1))) unsigned int*)g,
      (__attribute__((address_space(3))) unsigned int*)l, 16, 0, 0);
}

// ---------------- prep: x column-stats partials (blocks 0..127) + coeff cvt (blocks 128+) ----
// cvt folds K_n = exp(-2 c_n^2) into the fp16 coeffs.
__global__ __launch_bounds__(256) void prep_k(const float* __restrict__ c1, _Float16* __restrict__ d1, size_t n41,
                                              const float* __restrict__ c2, _Float16* __restrict__ d2, size_t n42,
                                              const float* __restrict__ X,
                                              float* __restrict__ ps, float* __restrict__ ps2) {
  const int bx = blockIdx.x;
  if (bx < 128) {
    // ---- stats on X: cols=256 (4 col-groups of 64), 32 row-segs of 512 ----
    int c     = (bx & 3) * 64 + (threadIdx.x & 63);
    int chunk = threadIdx.x >> 6;
    int seg   = bx >> 2;
    int r0    = seg * 512;
    double s = 0.0, s2 = 0.0;
    for (int r = r0 + chunk; r < r0 + 512; r += 4) {
      float v = X[(size_t)r * IN_DIM + c];
      s += v; s2 += (double)v * (double)v;
    }
    __shared__ float Ls[256], Ls2[256];
    Ls[threadIdx.x] = (float)s; Ls2[threadIdx.x] = (float)s2;
    __syncthreads();
    if (chunk == 0) {
      int cl = threadIdx.x;
      float a  = Ls[cl]  + Ls[cl + 64]  + Ls[cl + 128]  + Ls[cl + 192];
      float b  = Ls2[cl] + Ls2[cl + 64] + Ls2[cl + 128] + Ls2[cl + 192];
      ps [(size_t)seg * IN_DIM + c] = a;
      ps2[(size_t)seg * IN_DIM + c] = b;
    }
  } else {
    // ---- coeff conversion, grid-stride over remaining blocks ----
    size_t tot = n41 + n42;
    int nb_blocks = gridDim.x - 128;
    for (size_t i = (size_t)(bx - 128) * 256 + threadIdx.x; i < tot;
         i += (size_t)nb_blocks * 256) {
      const float4* sp; half4* dp; size_t j;
      if (i < n41) { sp = (const float4*)c1; dp = (half4*)d1; j = i; }
      else         { sp = (const float4*)c2; dp = (half4*)d2; j = i - n41; }
      float4 v = sp[j];
      int nb = (int)((j << 2) & 15);
      half4 r;
      float e0 = -2.f + (float)(nb + 0) * (4.f / 15.f);
      float e1 = -2.f + (float)(nb + 1) * (4.f / 15.f);
      float e2 = -2.f + (float)(nb + 2) * (4.f / 15.f);
      float e3 = -2.f + (float)(nb + 3) * (4.f / 15.f);
      r[0] = (_Float16)(v.x * __expf(-2.f * e0 * e0));
      r[1] = (_Float16)(v.y * __expf(-2.f * e1 * e1));
      r[2] = (_Float16)(v.z * __expf(-2.f * e2 * e2));
      r[3] = (_Float16)(v.w * __expf(-2.f * e3 * e3));
      dp[j] = r;
    }
  }
}

// ---------------- stats finalize (float partials) ----------------
__global__ void stats_final_k(const float* __restrict__ ps,
                              const float* __restrict__ ps2,
                              int segs, int cols, int rows,
                              float* __restrict__ mu, float* __restrict__ isd) {
  int c = blockIdx.x * blockDim.x + threadIdx.x;
  if (c >= cols) return;
  double s = 0.0, s2 = 0.0;
  for (int g = 0; g < segs; g++) { s += ps[(size_t)g * cols + c]; s2 += ps2[(size_t)g * cols + c]; }
  double mean = s / rows;
  double var  = (s2 - s * s / rows) / (rows - 1);   // ddof=1
  if (var < 0.0) var = 0.0;
  float sd = (float)sqrt(var);
  mu[c]  = (float)mean;
  isd[c] = 1.0f / (sd + 1e-6f);
}

// ---------------- fused normalize+expand+GEMM+tanh + column-stats partials ----------------
// H[b, o] = tanh( sum_k basis(xn[b, k/16])_[k%16] * Cb[o, k] ),  K = C*16
// 128x128 tile, 256 threads (4 waves 2x2), grid (B/128, 4) = 512 blocks = 2 blocks/CU.
// R7: BK 32 -> 64. The BK=32 loop measured ~2000 cyc/step-pair with only ~620 cyc of
// MFMA issue (MfmaUtil 28%) -- the ~800-cyc fixed per-barrier drain/arrival cost was
// the limiter, not any pipe. Doubling MFMA per barrier halves the barrier count.
// LDS 66 KB (<= 80 KB) keeps 2 blocks/CU.
// A: K-major LDS (0-conflict: bank group = 4*(lrow&7), kseg term vanishes mod 32).
// B: XOR swizzle seg' = s ^ ((row>>1)&7) over 8 segs (coalesced DMA + min-conflict
// frag reads: bank group = 4*seg', row term = 32*row vanishes mod 32).
// s_setprio(1) around the MFMA cluster: 2 co-resident blocks are at different phases
// (one expanding on VALU while the other MFMAs) -> genuine role split (T5 regime).
// Epilogue: fused per-block column sums of h and h^2 -> psum/psum2 (f32) for next layer's stats.
__global__ __launch_bounds__(256, 2) void kan_gemm_fused(const float* __restrict__ X,   // [B, C]
                                                         const float* __restrict__ mu,
                                                         const float* __restrict__ isd,
                                                         const _Float16* __restrict__ Bm, // [512, C*16]
                                                         float* __restrict__ Hout,        // [B, 512]
                                                         float* __restrict__ psum,        // [128, 512]
                                                         float* __restrict__ psum2,       // [128, 512]
                                                         int C) {
  const int K = C << 4;
  const int steps = K >> 6;                 // BK = 64
  __shared__ __align__(16) _Float16 As[2][128 * 64];   // 32 KB; chunk = kseg*128 + row, kseg 0..7
  __shared__ __align__(16) _Float16 Bs[2][128 * 64];   // 32 KB; chunk = row*8 + swizzled seg
  __shared__ float Rs1[2][128], Rs2[2][128];           //  2 KB epilogue reduction
  const int tid  = threadIdx.x;
  const int w = tid >> 6, lane = tid & 63;
  const int wm = w & 1, wn = w >> 1;        // 2x2 wave grid
  const int lrow = lane & 15, quad = lane >> 4;
  const int row0 = blockIdx.x * 128;
  const int col0 = blockIdx.y * 128;

  // ---- B staging: buffer = 1024 chunks of 16B; thread owns chunks tid + 256*i.
  //      chunk c = row*8 + sl holds global seg = sl ^ ((row>>1)&7); rows step by 32
  //      per i so ((row>>1)&7) is invariant -> one seg for all 4 chunks.
  const int s_row = tid >> 3;               // 0..31
  const int s_sl  = tid & 7;
  const int s_seg = s_sl ^ ((s_row >> 1) & 7);
  const _Float16* gB = Bm + (size_t)(col0 + s_row) * K + s_seg * 8;

  // ---- A expansion: thread -> row = tid>>1, col-pair eh = tid&1; step k covers x-cols
  //      [4k, 4k+4); this thread expands cols 4k+2eh, 4k+2eh+1 -> ksegs 4eh..4eh+3.
  const int erow = tid >> 1, eh = tid & 1;
  const float* xp  = X   + (size_t)(row0 + erow) * C + 2 * eh;  // step k: xp[4k], xp[4k+1]
  const float* mup = mu  + 2 * eh;
  const float* isp = isd + 2 * eh;

  floatx4 acc[4][4] = {};

  auto expand_store = [&](float2 v, float2 m, float2 sdi, int bufi) {
#pragma unroll
    for (int h = 0; h < 2; h++) {
      float xr = h ? v.y : v.x;
      float mm = h ? m.y : m.x;
      float ii = h ? sdi.y : sdi.x;
      float xn = fminf(fmaxf((xr - mm) * ii, -3.f), 3.f);
      float Wv = __expf(-2.f * xn * xn - 8.f * xn);
      float g  = __expf((16.f / 15.f) * xn);
      half8 h0, h1;
      float p = Wv;
#pragma unroll
      for (int n = 0; n < 8; n++) { h0[n] = (_Float16)p; p *= g; }
#pragma unroll
      for (int n = 0; n < 8; n++) { h1[n] = (_Float16)p; p *= g; }
      int ks0 = 4 * eh + 2 * h;
      *(half8*)&As[bufi][(size_t)(ks0 * 128 + erow) * 8]       = h0;
      *(half8*)&As[bufi][(size_t)((ks0 + 1) * 128 + erow) * 8] = h1;
    }
  };

  // ---- prologue: fill buffer 0 ----
#pragma unroll
  for (int i = 0; i < 4; i++)
    gld16(gB + (size_t)32 * i * K, &Bs[0][(size_t)(tid + 256 * i) * 8]);
  expand_store(*(const float2*)xp, *(const float2*)mup, *(const float2*)isp, 0);
  float2 xv = {}, mv = {}, iv = {};
  if (steps > 1) {
    xv = *(const float2*)(xp + 4);
    mv = *(const float2*)(mup + 4);
    iv = *(const float2*)(isp + 4);
  }
  __syncthreads();

  // ---- main loop: one barrier per BK=64 step; DMA+expand for k+1 issued before MFMA of k ----
  for (int k = 0; k < steps; k++) {
    const int buf = k & 1, nb = buf ^ 1;
    if (k + 1 < steps) {
#pragma unroll
      for (int i = 0; i < 4; i++)
        gld16(gB + (size_t)(k + 1) * 64 + (size_t)32 * i * K,
              &Bs[nb][(size_t)(tid + 256 * i) * 8]);
      expand_store(xv, mv, iv, nb);
      if (k + 2 < steps) {
        xv = *(const float2*)(xp + 4 * (k + 2));
        mv = *(const float2*)(mup + 4 * (k + 2));
        iv = *(const float2*)(isp + 4 * (k + 2));
      }
    }
    __builtin_amdgcn_s_setprio(1);
#pragma unroll
    for (int ks = 0; ks < 2; ks++) {
      half8 af[4], bf[4];
#pragma unroll
      for (int t = 0; t < 4; t++) {
        int arow = wm * 64 + t * 16 + lrow;
        af[t] = *(const half8*)&As[buf][(size_t)((4 * ks + quad) * 128 + arow) * 8];
        int brow = wn * 64 + t * 16 + lrow;
        int bchunk = brow * 8 + ((4 * ks + quad) ^ ((brow >> 1) & 7));
        bf[t] = *(const half8*)&Bs[buf][(size_t)bchunk * 8];
      }
#pragma unroll
      for (int tm = 0; tm < 4; tm++)
#pragma unroll
        for (int tn = 0; tn < 4; tn++)
          acc[tm][tn] = __builtin_amdgcn_mfma_f32_16x16x32_f16(af[tm], bf[tn], acc[tm][tn], 0, 0, 0);
    }
    __builtin_amdgcn_s_setprio(0);
    __syncthreads();
  }

  // ---- epilogue: C/D layout col=lane&15, row=quad*4+reg; fused tanh + column partial sums ----
  float s1[4] = {0.f, 0.f, 0.f, 0.f}, s2v[4] = {0.f, 0.f, 0.f, 0.f};
#pragma unroll
  for (int tm = 0; tm < 4; tm++) {
#pragma unroll
    for (int tn = 0; tn < 4; tn++) {
      int gcol = col0 + wn * 64 + tn * 16 + lrow;
#pragma unroll
      for (int r = 0; r < 4; r++) {
        int grow = row0 + wm * 64 + tm * 16 + quad * 4 + r;
        float v = fast_tanh(acc[tm][tn][r]);
        Hout[(size_t)grow * H_DIM + gcol] = v;
        s1[tn] += v; s2v[tn] += v * v;
      }
    }
  }
  // reduce over quad (rows within the wave's 64-row span)
#pragma unroll
  for (int tn = 0; tn < 4; tn++) {
    s1[tn]  += __shfl_xor(s1[tn], 16);  s1[tn]  += __shfl_xor(s1[tn], 32);
    s2v[tn] += __shfl_xor(s2v[tn], 16); s2v[tn] += __shfl_xor(s2v[tn], 32);
  }
  if (quad == 0) {
#pragma unroll
    for (int tn = 0; tn < 4; tn++) {
      Rs1[wm][wn * 64 + tn * 16 + lrow] = s1[tn];
      Rs2[wm][wn * 64 + tn * 16 + lrow] = s2v[tn];
    }
  }
  __syncthreads();
  if (tid < 128) {
    psum [(size_t)blockIdx.x * H_DIM + col0 + tid] = Rs1[0][tid] + Rs1[1][tid];
    psum2[(size_t)blockIdx.x * H_DIM + col0 + tid] = Rs2[0][tid] + Rs2[1][tid];
  }
}

// ---------------- layer 3 (out dim 1) + skip, fp32, normalize fused ----------------
__global__ __launch_bounds__(256) void layer3_k(const float* __restrict__ H2,
                                                const float* __restrict__ mu,
                                                const float* __restrict__ isd,
                                                const float* __restrict__ C3,
                                                const float* __restrict__ X,
                                                const float* __restrict__ SW,
                                                const float* __restrict__ SB,
                                                float* __restrict__ OUT) {
  int w = threadIdx.x >> 6, lane = threadIdx.x & 63;
  float Kn[NB];
#pragma unroll
  for (int n = 0; n < NB; n++) {
    float c = -2.f + (float)n * (4.f / 15.f);
    Kn[n] = __expf(-2.f * c * c);
  }
  float sb0 = SB[0];
  int row_base = blockIdx.x * 16 + w * 4;
  for (int r = 0; r < 4; r++) {
    int row = row_base + r;
    float s = 0.f;
#pragma unroll
    for (int j = 0; j < 8; j++) {
      int i = lane + 64 * j;
      float hv = H2[(size_t)row * H_DIM + i];
      float xn = fminf(fmaxf((hv - mu[i]) * isd[i], -3.f), 3.f);
      float Wf = __expf(-2.f * xn * xn - 8.f * xn);
      float gf = __expf((16.f / 15.f) * xn);
      const floatx4* cp = (const floatx4*)(C3 + (size_t)i * NB);
      floatx4 c0 = cp[0], c1 = cp[1], c2 = cp[2], c3 = cp[3];
      float p = Wf;
#pragma unroll
      for (int n = 0; n < 4; n++) { s += p * Kn[n]      * c0[n]; p *= gf; }
#pragma unroll
      for (int n = 0; n < 4; n++) { s += p * Kn[n + 4]  * c1[n]; p *= gf; }
#pragma unroll
      for (int n = 0; n < 4; n++) { s += p * Kn[n + 8]  * c2[n]; p *= gf; }
#pragma unroll
      for (int n = 0; n < 4; n++) { s += p * Kn[n + 12] * c3[n]; p *= gf; }
    }
#pragma unroll
    for (int j = 0; j < 4; j++) {
      int i = lane + 64 * j;
      s += X[(size_t)row * IN_DIM + i] * SW[i];
    }
#pragma unroll
    for (int off = 32; off > 0; off >>= 1) s += __shfl_down(s, off);
    if (lane == 0) OUT[row] = s + sb0;
  }
}

// ---------------- launcher ----------------
extern "C" void kernel_launch(void* const* d_in, const int* in_sizes, int n_in,
                              void* d_out, int out_size, void* d_ws, size_t ws_size,
                              hipStream_t stream) {
  const float* x  = (const float*)d_in[0];   // [16384, 256]
  const float* c1 = (const float*)d_in[1];   // [512, 256, 16]
  const float* c2 = (const float*)d_in[2];   // [512, 512, 16]
  const float* c3 = (const float*)d_in[3];   // [1, 512, 16]
  const float* sw = (const float*)d_in[4];   // [1, 256]
  const float* sb = (const float*)d_in[5];   // [1]
  float* out = (float*)d_out;

  const int B = B_ROWS, IN = IN_DIM, H = H_DIM;

  char* ws = (char*)d_ws;
  size_t off = 0;
  auto alloc = [&](size_t bytes) -> void* {
    void* p = ws + off;
    off += (bytes + 255) & ~(size_t)255;
    return p;
  };
  _Float16* C1h = (_Float16*)alloc((size_t)H * IN * NB * 2);  //  4 MB
  _Float16* C2h = (_Float16*)alloc((size_t)H * H  * NB * 2);  //  8 MB
  float* H1 = (float*)alloc((size_t)B * H * 4);               // 32 MB
  float* H2 = (float*)alloc((size_t)B * H * 4);               // 32 MB
  float* ps  = (float*)alloc(128 * 512 * 4);                  // 256 KB
  float* ps2 = (float*)alloc(128 * 512 * 4);
  float* mu  = (float*)alloc(512 * 4);
  float* isd = (float*)alloc(512 * 4);

  // ---- prep: x-stats partials + coeff cvt in one dispatch ----
  prep_k<<<128 + 1024, 256, 0, stream>>>(c1, C1h, (size_t)H * IN * NB / 4,
                                         c2, C2h, (size_t)H * H * NB / 4,
                                         x, ps, ps2);
  stats_final_k<<<1, 256, 0, stream>>>(ps, ps2, 32, IN, B, mu, isd);

  // ---- layer 1 (C=256, K=4096); epilogue emits H1 column partials ----
  kan_gemm_fused<<<dim3(B / 128, 4), 256, 0, stream>>>(x, mu, isd, C1h, H1, ps, ps2, IN);
  stats_final_k<<<2, 256, 0, stream>>>(ps, ps2, 128, H, B, mu, isd);

  // ---- layer 2 (C=512, K=8192); epilogue emits H2 column partials ----
  kan_gemm_fused<<<dim3(B / 128, 4), 256, 0, stream>>>(H1, mu, isd, C2h, H2, ps, ps2, H);
  stats_final_k<<<2, 256, 0, stream>>>(ps, ps2, 128, H, B, mu, isd);

  // ---- layer 3 + skip (normalize fused) ----
  layer3_k<<<B / 16, 256, 0, stream>>>(H2, mu, isd, c3, x, sw, sb, out);
}